// Round 1
// baseline (530.065 us; speedup 1.0000x reference)
//
#include <hip/hip_runtime.h>
#include <math.h>

#define NTOK   4096      // B*S
#define DMODEL 1024
#define DFFN   2048
#define NEXP   8         // FFN experts
#define ETOT   12        // total experts (8 FFN + 4 zero)
#define MAXA   8192      // max assignments (NTOK * TOP_K)

typedef short  bf16x8 __attribute__((ext_vector_type(8)));
typedef float  f32x4  __attribute__((ext_vector_type(4)));

__device__ __forceinline__ unsigned short f2bf(float f) {
  unsigned int u = __float_as_uint(f);
  unsigned int r = (u + 0x7fffu + ((u >> 16) & 1u)) >> 16;  // RNE
  return (unsigned short)r;
}

// ---------------- routing: logits, top-2, softmax ----------------
__global__ void route_kernel(const float* __restrict__ x,
                             const float* __restrict__ gw,
                             const float* __restrict__ eb,
                             int* __restrict__ cnt,
                             int* __restrict__ choice,
                             float* __restrict__ chw,
                             float* __restrict__ wz) {
  int gid  = blockIdx.x * blockDim.x + threadIdx.x;
  int tok  = gid >> 6;
  int lane = threadIdx.x & 63;
  if (tok >= NTOK) return;
  const float* xr = x + (size_t)tok * DMODEL;
  float lg[ETOT];
  #pragma unroll
  for (int e = 0; e < ETOT; e++) {
    const float* gr = gw + e * DMODEL;
    float s = 0.f;
    for (int d = lane; d < DMODEL; d += 64) s += xr[d] * gr[d];
    #pragma unroll
    for (int m = 32; m >= 1; m >>= 1) s += __shfl_xor(s, m, 64);
    lg[e] = s + eb[e];
  }
  // top-2, ties -> lowest index (matches jax.lax.top_k)
  int i1 = 0; float m1 = lg[0];
  #pragma unroll
  for (int e = 1; e < ETOT; e++) if (lg[e] > m1) { m1 = lg[e]; i1 = e; }
  int i2 = -1; float m2 = -3.4e38f;
  #pragma unroll
  for (int e = 0; e < ETOT; e++) { if (e == i1) continue; if (lg[e] > m2) { m2 = lg[e]; i2 = e; } }
  float ex = expf(m2 - m1);
  float w0 = 1.f / (1.f + ex);
  float w1 = ex / (1.f + ex);
  if (lane == 0) {
    int ee[2] = { i1, i2 };
    float ww[2] = { w0, w1 };
    float z = 0.f;
    #pragma unroll
    for (int k = 0; k < 2; k++) {
      choice[tok * 2 + k] = ee[k];
      chw[tok * 2 + k]    = ww[k];
      if (ee[k] < NEXP) atomicAdd(&cnt[ee[k]], 1);
      else              z += ww[k];
    }
    wz[tok] = z;
  }
}

// ---------------- tiny exclusive scan over 8 counts ----------------
__global__ void scan_kernel(const int* __restrict__ cnt,
                            int* __restrict__ offs,
                            int* __restrict__ cursor) {
  if (threadIdx.x == 0) {
    int a = 0;
    for (int e = 0; e < NEXP; e++) { offs[e] = a; cursor[e] = a; a += cnt[e]; }
  }
}

// ---------------- slot assignment (order nondeterministic, values not) ----
__global__ void assign_kernel(const int* __restrict__ choice,
                              int* __restrict__ cursor,
                              int* __restrict__ a_row,
                              int* __restrict__ tok_list) {
  int t = blockIdx.x * blockDim.x + threadIdx.x;
  if (t >= NTOK) return;
  #pragma unroll
  for (int k = 0; k < 2; k++) {
    int e = choice[2 * t + k];
    if (e < NEXP) {
      int pos = atomicAdd(&cursor[e], 1);
      a_row[2 * t + k] = pos;
      tok_list[pos] = t;
    } else {
      a_row[2 * t + k] = -1;
    }
  }
}

// ---------------- grouped GEMM (B^T layout), 64x64 tile, mfma 16x16x32 ----
// NDIM: output cols, KDIM: reduction. AGATHER: A rows gathered from x via
// tok_list (fp32) else direct bf16 rows of H. SILU -> write bf16 H, else f32 Y.
template <int NDIM, int KDIM, bool SILU, bool AGATHER>
__launch_bounds__(256)
__global__ void ffn_gemm(const float* __restrict__ Af32,
                         const unsigned short* __restrict__ Abf,
                         const float* __restrict__ Bw,
                         const int* __restrict__ cnt,
                         const int* __restrict__ offs,
                         const int* __restrict__ tok_list,
                         unsigned short* __restrict__ OutBf,
                         float* __restrict__ OutF) {
  int e = blockIdx.z;
  int count = cnt[e];
  int m0 = blockIdx.x * 64;
  if (m0 >= count) return;
  int off = offs[e];
  int n0 = blockIdx.y * 64;
  const float* B = Bw + (size_t)e * NDIM * KDIM;

  __shared__ unsigned short lA[64][40];   // +8 pad: bank spread, 16B-aligned rows
  __shared__ unsigned short lB[64][40];

  int tid  = threadIdx.x;
  int lane = tid & 63;
  int wv = tid >> 6;
  int wm = wv >> 1, wn = wv & 1;
  int lr = lane & 15, lk8 = (lane >> 4) * 8;

  // each thread stages 2 A-chunks and 2 B-chunks of 4 elems per K-step
  int row0 = tid >> 3,            kc0 = tid & 7;
  int row1 = (tid + 256) >> 3,    kc1 = tid & 7;
  int mr0 = m0 + row0; if (mr0 >= count) mr0 = count - 1;
  int mr1 = m0 + row1; if (mr1 >= count) mr1 = count - 1;
  const float*          a0f = nullptr; const float*          a1f = nullptr;
  const unsigned short* a0h = nullptr; const unsigned short* a1h = nullptr;
  if (AGATHER) {
    a0f = Af32 + (size_t)tok_list[off + mr0] * KDIM;
    a1f = Af32 + (size_t)tok_list[off + mr1] * KDIM;
  } else {
    a0h = Abf + (size_t)(off + mr0) * KDIM;
    a1h = Abf + (size_t)(off + mr1) * KDIM;
  }
  const float* b0 = B + (size_t)(n0 + row0) * KDIM;
  const float* b1 = B + (size_t)(n0 + row1) * KDIM;

  f32x4 acc[2][2] = {};

  for (int kk = 0; kk < KDIM / 32; kk++) {
    __syncthreads();
    int kb = kk * 32;
    // --- stage A ---
    if (AGATHER) {
      float4 v0 = *(const float4*)(a0f + kb + kc0 * 4);
      float4 v1 = *(const float4*)(a1f + kb + kc1 * 4);
      ushort4 u0; u0.x = f2bf(v0.x); u0.y = f2bf(v0.y); u0.z = f2bf(v0.z); u0.w = f2bf(v0.w);
      ushort4 u1; u1.x = f2bf(v1.x); u1.y = f2bf(v1.y); u1.z = f2bf(v1.z); u1.w = f2bf(v1.w);
      *(ushort4*)&lA[row0][kc0 * 4] = u0;
      *(ushort4*)&lA[row1][kc1 * 4] = u1;
    } else {
      *(ushort4*)&lA[row0][kc0 * 4] = *(const ushort4*)(a0h + kb + kc0 * 4);
      *(ushort4*)&lA[row1][kc1 * 4] = *(const ushort4*)(a1h + kb + kc1 * 4);
    }
    // --- stage B (fp32 weights -> bf16) ---
    {
      float4 v0 = *(const float4*)(b0 + kb + kc0 * 4);
      float4 v1 = *(const float4*)(b1 + kb + kc1 * 4);
      ushort4 u0; u0.x = f2bf(v0.x); u0.y = f2bf(v0.y); u0.z = f2bf(v0.z); u0.w = f2bf(v0.w);
      ushort4 u1; u1.x = f2bf(v1.x); u1.y = f2bf(v1.y); u1.z = f2bf(v1.z); u1.w = f2bf(v1.w);
      *(ushort4*)&lB[row0][kc0 * 4] = u0;
      *(ushort4*)&lB[row1][kc1 * 4] = u1;
    }
    __syncthreads();
    bf16x8 af[2], bfr[2];
    #pragma unroll
    for (int mi = 0; mi < 2; mi++) af[mi]  = *(const bf16x8*)&lA[wm * 32 + mi * 16 + lr][lk8];
    #pragma unroll
    for (int ni = 0; ni < 2; ni++) bfr[ni] = *(const bf16x8*)&lB[wn * 32 + ni * 16 + lr][lk8];
    #pragma unroll
    for (int mi = 0; mi < 2; mi++)
      #pragma unroll
      for (int ni = 0; ni < 2; ni++)
        acc[mi][ni] = __builtin_amdgcn_mfma_f32_16x16x32_bf16(af[mi], bfr[ni], acc[mi][ni], 0, 0, 0);
  }

  // epilogue: C/D layout col=lane&15, row=(lane>>4)*4+i  [m89-verified]
  int rb = (lane >> 4) * 4;
  #pragma unroll
  for (int mi = 0; mi < 2; mi++) {
    #pragma unroll
    for (int i = 0; i < 4; i++) {
      int lrow = wm * 32 + mi * 16 + rb + i;
      int grow = m0 + lrow;
      if (grow >= count) continue;
      #pragma unroll
      for (int ni = 0; ni < 2; ni++) {
        int gcol = n0 + wn * 32 + ni * 16 + lr;
        float v = acc[mi][ni][i];
        if (SILU) {
          float s = v / (1.f + expf(-v));
          OutBf[(size_t)(off + grow) * NDIM + gcol] = f2bf(s);
        } else {
          OutF[(size_t)(off + grow) * NDIM + gcol] = v;
        }
      }
    }
  }
}

// ---------------- final combine: out = wz*x + sum_k w_k * Y[row_k] --------
__global__ void combine_kernel(const float* __restrict__ x,
                               const float* __restrict__ Y,
                               const int* __restrict__ a_row,
                               const float* __restrict__ chw,
                               const float* __restrict__ wz,
                               float* __restrict__ out) {
  int t = blockIdx.x;
  int d = threadIdx.x * 4;
  const float4 xv = *(const float4*)&x[(size_t)t * DMODEL + d];
  float z = wz[t];
  float4 o; o.x = z * xv.x; o.y = z * xv.y; o.z = z * xv.z; o.w = z * xv.w;
  #pragma unroll
  for (int k = 0; k < 2; k++) {
    int r = a_row[2 * t + k];
    if (r >= 0) {
      float w = chw[2 * t + k];
      const float4 yv = *(const float4*)&Y[(size_t)r * DMODEL + d];
      o.x += w * yv.x; o.y += w * yv.y; o.z += w * yv.z; o.w += w * yv.w;
    }
  }
  *(float4*)&out[(size_t)t * DMODEL + d] = o;
}

extern "C" void kernel_launch(void* const* d_in, const int* in_sizes, int n_in,
                              void* d_out, int out_size, void* d_ws, size_t ws_size,
                              hipStream_t stream) {
  const float* x  = (const float*)d_in[0];   // (2,2048,1024)
  const float* gw = (const float*)d_in[1];   // (12,1024)
  const float* eb = (const float*)d_in[2];   // (12,)
  const float* w1 = (const float*)d_in[3];   // (8,2048,1024)
  const float* w2 = (const float*)d_in[4];   // (8,1024,2048)
  float* out = (float*)d_out;

  char* ws = (char*)d_ws;
  size_t o = 0;
  int*   cnt     = (int*)(ws + o);  o += 8 * sizeof(int);
  int*   offs    = (int*)(ws + o);  o += 8 * sizeof(int);
  int*   cursor  = (int*)(ws + o);  o += 8 * sizeof(int);
  o = (o + 255) & ~(size_t)255;
  int*   choice  = (int*)(ws + o);  o += (size_t)2 * NTOK * sizeof(int);
  float* chw     = (float*)(ws + o); o += (size_t)2 * NTOK * sizeof(float);
  float* wzv     = (float*)(ws + o); o += (size_t)NTOK * sizeof(float);
  int*   a_row   = (int*)(ws + o);  o += (size_t)2 * NTOK * sizeof(int);
  int*   tok     = (int*)(ws + o);  o += (size_t)MAXA * sizeof(int);
  o = (o + 255) & ~(size_t)255;
  unsigned short* H = (unsigned short*)(ws + o); o += (size_t)MAXA * DFFN * sizeof(unsigned short);
  float*          Y = (float*)(ws + o);          o += (size_t)MAXA * DMODEL * sizeof(float);

  hipMemsetAsync(cnt, 0, 8 * sizeof(int), stream);

  route_kernel<<<dim3((NTOK * 64) / 256), dim3(256), 0, stream>>>(x, gw, eb, cnt, choice, chw, wzv);
  scan_kernel<<<dim3(1), dim3(64), 0, stream>>>(cnt, offs, cursor);
  assign_kernel<<<dim3(NTOK / 256), dim3(256), 0, stream>>>(choice, cursor, a_row, tok);

  // GEMM1: H = silu(x @ W1^T)   M<=cnt[e], N=2048, K=1024
  ffn_gemm<DFFN, DMODEL, true, true><<<dim3(64, DFFN / 64, NEXP), dim3(256), 0, stream>>>(
      x, nullptr, w1, cnt, offs, tok, H, nullptr);
  // GEMM2: Y = H @ W2^T         M<=cnt[e], N=1024, K=2048
  ffn_gemm<DMODEL, DFFN, false, false><<<dim3(64, DMODEL / 64, NEXP), dim3(256), 0, stream>>>(
      nullptr, H, w2, cnt, offs, tok, nullptr, Y);

  combine_kernel<<<dim3(NTOK), dim3(256), 0, stream>>>(x, Y, a_row, chw, wzv, out);
}

// Round 2
// 513.655 us; speedup vs baseline: 1.0319x; 1.0319x over previous
//
#include <hip/hip_runtime.h>
#include <math.h>

#define NTOK   4096      // B*S
#define DMODEL 1024
#define DFFN   2048
#define NEXP   8         // FFN experts
#define ETOT   12        // total experts (8 FFN + 4 zero)
#define MAXA   8192      // max assignments (NTOK * TOP_K)

typedef short  bf16x8 __attribute__((ext_vector_type(8)));
typedef float  f32x4  __attribute__((ext_vector_type(4)));

__device__ __forceinline__ unsigned short f2bf(float f) {
  unsigned int u = __float_as_uint(f);
  unsigned int r = (u + 0x7fffu + ((u >> 16) & 1u)) >> 16;  // RNE
  return (unsigned short)r;
}

#define G2L16(g, l)                                                        \
  __builtin_amdgcn_global_load_lds(                                        \
      (const __attribute__((address_space(1))) void*)(g),                  \
      (__attribute__((address_space(3))) void*)(l), 16, 0, 0)

// ---------------- fp32 -> bf16 bulk convert (8 elems/thread) -------------
__global__ void cvt_bf16_kernel(const float* __restrict__ in,
                                unsigned short* __restrict__ outp) {
  int i = blockIdx.x * blockDim.x + threadIdx.x;
  const float4* p = (const float4*)in;
  float4 v0 = p[2 * i], v1 = p[2 * i + 1];
  ushort4 u0, u1;
  u0.x = f2bf(v0.x); u0.y = f2bf(v0.y); u0.z = f2bf(v0.z); u0.w = f2bf(v0.w);
  u1.x = f2bf(v1.x); u1.y = f2bf(v1.y); u1.z = f2bf(v1.z); u1.w = f2bf(v1.w);
  ((ushort4*)outp)[2 * i]     = u0;
  ((ushort4*)outp)[2 * i + 1] = u1;
}

// ---------------- routing: logits, top-2, softmax ----------------
__global__ void route_kernel(const float* __restrict__ x,
                             const float* __restrict__ gw,
                             const float* __restrict__ eb,
                             int* __restrict__ cnt,
                             int* __restrict__ choice,
                             float* __restrict__ chw,
                             float* __restrict__ wz) {
  int gid  = blockIdx.x * blockDim.x + threadIdx.x;
  int tok  = gid >> 6;
  int lane = threadIdx.x & 63;
  if (tok >= NTOK) return;
  const float* xr = x + (size_t)tok * DMODEL;
  float xv[16];
  #pragma unroll
  for (int i = 0; i < 16; i++) xv[i] = xr[lane + i * 64];
  float lg[ETOT];
  #pragma unroll
  for (int e = 0; e < ETOT; e++) {
    const float* gr = gw + e * DMODEL;
    float s = 0.f;
    #pragma unroll
    for (int i = 0; i < 16; i++) s += xv[i] * gr[lane + i * 64];
    #pragma unroll
    for (int m = 32; m >= 1; m >>= 1) s += __shfl_xor(s, m, 64);
    lg[e] = s + eb[e];
  }
  // top-2, ties -> lowest index (matches jax.lax.top_k)
  int i1 = 0; float m1 = lg[0];
  #pragma unroll
  for (int e = 1; e < ETOT; e++) if (lg[e] > m1) { m1 = lg[e]; i1 = e; }
  int i2 = -1; float m2 = -3.4e38f;
  #pragma unroll
  for (int e = 0; e < ETOT; e++) { if (e == i1) continue; if (lg[e] > m2) { m2 = lg[e]; i2 = e; } }
  float ex = expf(m2 - m1);
  float w0 = 1.f / (1.f + ex);
  float w1 = ex / (1.f + ex);
  if (lane == 0) {
    int ee[2] = { i1, i2 };
    float ww[2] = { w0, w1 };
    float z = 0.f;
    #pragma unroll
    for (int k = 0; k < 2; k++) {
      choice[tok * 2 + k] = ee[k];
      chw[tok * 2 + k]    = ww[k];
      if (ee[k] < NEXP) atomicAdd(&cnt[ee[k]], 1);
      else              z += ww[k];
    }
    wz[tok] = z;
  }
}

// ---------------- tiny exclusive scan over 8 counts ----------------
__global__ void scan_kernel(const int* __restrict__ cnt,
                            int* __restrict__ offs,
                            int* __restrict__ cursor) {
  if (threadIdx.x == 0) {
    int a = 0;
    for (int e = 0; e < NEXP; e++) { offs[e] = a; cursor[e] = a; a += cnt[e]; }
  }
}

// ---------------- slot assignment (order nondeterministic, values not) ----
__global__ void assign_kernel(const int* __restrict__ choice,
                              int* __restrict__ cursor,
                              int* __restrict__ a_row,
                              int* __restrict__ tok_list) {
  int t = blockIdx.x * blockDim.x + threadIdx.x;
  if (t >= NTOK) return;
  #pragma unroll
  for (int k = 0; k < 2; k++) {
    int e = choice[2 * t + k];
    if (e < NEXP) {
      int pos = atomicAdd(&cursor[e], 1);
      a_row[2 * t + k] = pos;
      tok_list[pos] = t;
    } else {
      a_row[2 * t + k] = -1;
    }
  }
}

// ---------------- grouped GEMM, m97 structure: 128x128 tile, BK=32 --------
// bf16 inputs, global_load_lds(16B) staging, 4 waves x (4x4) 16x16x32 MFMA.
// AGATHER: A rows gathered from Xb via tok_list; else direct rows of H.
template <int NDIM, int KDIM, bool SILU, bool AGATHER>
__launch_bounds__(256)
__global__ void ffn_gemm(const unsigned short* __restrict__ Abf,
                         const unsigned short* __restrict__ Bw,
                         const int* __restrict__ cnt,
                         const int* __restrict__ offs,
                         const int* __restrict__ tok_list,
                         unsigned short* __restrict__ OutBf,
                         float* __restrict__ OutF) {
  int e = blockIdx.z;
  int count = cnt[e];
  int m0 = blockIdx.x * 128;
  if (m0 >= count) return;
  int off = offs[e];
  int n0 = blockIdx.y * 128;
  const unsigned short* B = Bw + (size_t)e * NDIM * KDIM;

  __shared__ unsigned short lA[128 * 32];   // linear: matches global_load_lds order
  __shared__ unsigned short lB[128 * 32];

  int tid  = threadIdx.x;
  int lane = tid & 63;
  int wv = tid >> 6;
  int wm = wv >> 1, wn = wv & 1;
  int lr = lane & 15, lk8 = (lane >> 4) * 8;

  // staging: issue j covers tile rows [j*64, j*64+64); thread -> row tid>>2, col (tid&3)*8
  int srow = tid >> 2;
  int scol = (tid & 3) * 8;
  const unsigned short* aSrc[2];
  const unsigned short* bSrc[2];
  #pragma unroll
  for (int j = 0; j < 2; j++) {
    int rr = m0 + j * 64 + srow;
    if (rr >= count) rr = count - 1;
    if (AGATHER) aSrc[j] = Abf + (size_t)tok_list[off + rr] * KDIM + scol;
    else         aSrc[j] = Abf + (size_t)(off + rr) * KDIM + scol;
    bSrc[j] = B + (size_t)(n0 + j * 64 + srow) * KDIM + scol;
  }

  f32x4 acc[4][4] = {};

  for (int kk = 0; kk < KDIM / 32; kk++) {
    int kb = kk * 32;
    __syncthreads();
    #pragma unroll
    for (int j = 0; j < 2; j++) {
      G2L16(aSrc[j] + kb, &lA[j * 2048 + tid * 8]);
      G2L16(bSrc[j] + kb, &lB[j * 2048 + tid * 8]);
    }
    __syncthreads();
    bf16x8 af[4], bq[4];
    #pragma unroll
    for (int mi = 0; mi < 4; mi++)
      af[mi] = *(const bf16x8*)&lA[(wm * 64 + mi * 16 + lr) * 32 + lk8];
    #pragma unroll
    for (int ni = 0; ni < 4; ni++)
      bq[ni] = *(const bf16x8*)&lB[(wn * 64 + ni * 16 + lr) * 32 + lk8];
    #pragma unroll
    for (int mi = 0; mi < 4; mi++)
      #pragma unroll
      for (int ni = 0; ni < 4; ni++)
        acc[mi][ni] = __builtin_amdgcn_mfma_f32_16x16x32_bf16(af[mi], bq[ni], acc[mi][ni], 0, 0, 0);
  }

  // epilogue: C/D layout col=lane&15, row=(lane>>4)*4+i  [m89-verified]
  int rb = (lane >> 4) * 4;
  #pragma unroll
  for (int mi = 0; mi < 4; mi++) {
    #pragma unroll
    for (int i = 0; i < 4; i++) {
      int grow = m0 + wm * 64 + mi * 16 + rb + i;
      if (grow >= count) continue;
      #pragma unroll
      for (int ni = 0; ni < 4; ni++) {
        int gcol = n0 + wn * 64 + ni * 16 + lr;
        float v = acc[mi][ni][i];
        if (SILU) {
          float s = v / (1.f + expf(-v));
          OutBf[(size_t)(off + grow) * NDIM + gcol] = f2bf(s);
        } else {
          OutF[(size_t)(off + grow) * NDIM + gcol] = v;
        }
      }
    }
  }
}

// ---------------- final combine: out = wz*x + sum_k w_k * Y[row_k] --------
__global__ void combine_kernel(const float* __restrict__ x,
                               const float* __restrict__ Y,
                               const int* __restrict__ a_row,
                               const float* __restrict__ chw,
                               const float* __restrict__ wz,
                               float* __restrict__ out) {
  int t = blockIdx.x;
  int d = threadIdx.x * 4;
  const float4 xv = *(const float4*)&x[(size_t)t * DMODEL + d];
  float z = wz[t];
  float4 o; o.x = z * xv.x; o.y = z * xv.y; o.z = z * xv.z; o.w = z * xv.w;
  #pragma unroll
  for (int k = 0; k < 2; k++) {
    int r = a_row[2 * t + k];
    if (r >= 0) {
      float w = chw[2 * t + k];
      const float4 yv = *(const float4*)&Y[(size_t)r * DMODEL + d];
      o.x += w * yv.x; o.y += w * yv.y; o.z += w * yv.z; o.w += w * yv.w;
    }
  }
  *(float4*)&out[(size_t)t * DMODEL + d] = o;
}

extern "C" void kernel_launch(void* const* d_in, const int* in_sizes, int n_in,
                              void* d_out, int out_size, void* d_ws, size_t ws_size,
                              hipStream_t stream) {
  const float* x  = (const float*)d_in[0];   // (2,2048,1024)
  const float* gw = (const float*)d_in[1];   // (12,1024)
  const float* eb = (const float*)d_in[2];   // (12,)
  const float* w1 = (const float*)d_in[3];   // (8,2048,1024)
  const float* w2 = (const float*)d_in[4];   // (8,1024,2048)
  float* out = (float*)d_out;

  char* ws = (char*)d_ws;
  size_t o = 0;
  int*   cnt     = (int*)(ws + o);  o += 8 * sizeof(int);
  int*   offs    = (int*)(ws + o);  o += 8 * sizeof(int);
  int*   cursor  = (int*)(ws + o);  o += 8 * sizeof(int);
  o = (o + 255) & ~(size_t)255;
  int*   choice  = (int*)(ws + o);  o += (size_t)2 * NTOK * sizeof(int);
  float* chw     = (float*)(ws + o); o += (size_t)2 * NTOK * sizeof(float);
  float* wzv     = (float*)(ws + o); o += (size_t)NTOK * sizeof(float);
  int*   a_row   = (int*)(ws + o);  o += (size_t)2 * NTOK * sizeof(int);
  int*   tok     = (int*)(ws + o);  o += (size_t)MAXA * sizeof(int);
  o = (o + 255) & ~(size_t)255;
  unsigned short* Xb  = (unsigned short*)(ws + o); o += (size_t)NTOK * DMODEL * sizeof(unsigned short);
  unsigned short* W1b = (unsigned short*)(ws + o); o += (size_t)NEXP * DFFN * DMODEL * sizeof(unsigned short);
  unsigned short* W2b = (unsigned short*)(ws + o); o += (size_t)NEXP * DMODEL * DFFN * sizeof(unsigned short);
  unsigned short* H   = (unsigned short*)(ws + o); o += (size_t)MAXA * DFFN * sizeof(unsigned short);
  // Y aliases W1b (33.55 MB each): W1b is dead after GEMM1, GEMM2 reads only H+W2b.
  float* Y = (float*)W1b;

  hipMemsetAsync(cnt, 0, 8 * sizeof(int), stream);

  cvt_bf16_kernel<<<dim3((NEXP * DFFN * DMODEL) / (8 * 256)), dim3(256), 0, stream>>>(w1, W1b);
  cvt_bf16_kernel<<<dim3((NEXP * DMODEL * DFFN) / (8 * 256)), dim3(256), 0, stream>>>(w2, W2b);
  cvt_bf16_kernel<<<dim3((NTOK * DMODEL) / (8 * 256)), dim3(256), 0, stream>>>(x, Xb);

  route_kernel<<<dim3((NTOK * 64) / 256), dim3(256), 0, stream>>>(x, gw, eb, cnt, choice, chw, wzv);
  scan_kernel<<<dim3(1), dim3(64), 0, stream>>>(cnt, offs, cursor);
  assign_kernel<<<dim3(NTOK / 256), dim3(256), 0, stream>>>(choice, cursor, a_row, tok);

  // GEMM1: H = silu(Xb @ W1b^T)   M<=cnt[e], N=2048, K=1024
  ffn_gemm<DFFN, DMODEL, true, true><<<dim3(32, DFFN / 128, NEXP), dim3(256), 0, stream>>>(
      Xb, W1b, cnt, offs, tok, H, nullptr);
  // GEMM2: Y = H @ W2b^T          M<=cnt[e], N=1024, K=2048
  ffn_gemm<DMODEL, DFFN, false, false><<<dim3(32, DMODEL / 128, NEXP), dim3(256), 0, stream>>>(
      H, W2b, cnt, offs, tok, nullptr, Y);

  combine_kernel<<<dim3(NTOK), dim3(256), 0, stream>>>(x, Y, a_row, chw, wzv, out);
}

// Round 4
// 263.343 us; speedup vs baseline: 2.0128x; 1.9505x over previous
//
#include <hip/hip_runtime.h>
#include <math.h>

#define NTOK   4096      // B*S
#define DMODEL 1024
#define DFFN   2048
#define NEXP   8         // FFN experts
#define ETOT   12        // total experts (8 FFN + 4 zero)
#define MAXA   8192      // max assignments (NTOK * TOP_K)

typedef short  bf16x8 __attribute__((ext_vector_type(8)));
typedef float  f32x4  __attribute__((ext_vector_type(4)));

__device__ __forceinline__ unsigned short f2bf(float f) {
  unsigned int u = __float_as_uint(f);
  unsigned int r = (u + 0x7fffu + ((u >> 16) & 1u)) >> 16;  // RNE
  return (unsigned short)r;
}

#define G2L16(g, l)                                                        \
  __builtin_amdgcn_global_load_lds(                                        \
      (const __attribute__((address_space(1))) void*)(g),                  \
      (__attribute__((address_space(3))) void*)(l), 16, 0, 0)

// ---------------- fp32 -> bf16 bulk convert (grid-stride, 8 elems/thr) ----
__global__ void cvt_bf16_kernel(const float* __restrict__ in,
                                unsigned short* __restrict__ outp, int n8) {
  for (int i = blockIdx.x * blockDim.x + threadIdx.x; i < n8;
       i += gridDim.x * blockDim.x) {
    const float4* p = (const float4*)in;
    float4 v0 = p[2 * i], v1 = p[2 * i + 1];
    ushort4 u0, u1;
    u0.x = f2bf(v0.x); u0.y = f2bf(v0.y); u0.z = f2bf(v0.z); u0.w = f2bf(v0.w);
    u1.x = f2bf(v1.x); u1.y = f2bf(v1.y); u1.z = f2bf(v1.z); u1.w = f2bf(v1.w);
    ((ushort4*)outp)[2 * i]     = u0;
    ((ushort4*)outp)[2 * i + 1] = u1;
  }
}

// ---------------- routing: logits, top-2, softmax ----------------
__global__ void route_kernel(const float* __restrict__ x,
                             const float* __restrict__ gw,
                             const float* __restrict__ eb,
                             int* __restrict__ cnt,
                             int* __restrict__ choice,
                             float* __restrict__ chw,
                             float* __restrict__ wz) {
  int gid  = blockIdx.x * blockDim.x + threadIdx.x;
  int tok  = gid >> 6;
  int lane = threadIdx.x & 63;
  if (tok >= NTOK) return;
  const float* xr = x + (size_t)tok * DMODEL;
  float xv[16];
  #pragma unroll
  for (int i = 0; i < 16; i++) xv[i] = xr[lane + i * 64];
  float lg[ETOT];
  #pragma unroll
  for (int e = 0; e < ETOT; e++) {
    const float* gr = gw + e * DMODEL;
    float s = 0.f;
    #pragma unroll
    for (int i = 0; i < 16; i++) s += xv[i] * gr[lane + i * 64];
    #pragma unroll
    for (int m = 32; m >= 1; m >>= 1) s += __shfl_xor(s, m, 64);
    lg[e] = s + eb[e];
  }
  int i1 = 0; float m1 = lg[0];
  #pragma unroll
  for (int e = 1; e < ETOT; e++) if (lg[e] > m1) { m1 = lg[e]; i1 = e; }
  int i2 = -1; float m2 = -3.4e38f;
  #pragma unroll
  for (int e = 0; e < ETOT; e++) { if (e == i1) continue; if (lg[e] > m2) { m2 = lg[e]; i2 = e; } }
  float ex = expf(m2 - m1);
  float w0 = 1.f / (1.f + ex);
  float w1 = ex / (1.f + ex);
  if (lane == 0) {
    int ee[2] = { i1, i2 };
    float ww[2] = { w0, w1 };
    float z = 0.f;
    #pragma unroll
    for (int k = 0; k < 2; k++) {
      choice[tok * 2 + k] = ee[k];
      chw[tok * 2 + k]    = ww[k];
      if (ee[k] < NEXP) atomicAdd(&cnt[ee[k]], 1);
      else              z += ww[k];
    }
    wz[tok] = z;
  }
}

// ---------------- tiny exclusive scan over 8 counts ----------------
__global__ void scan_kernel(const int* __restrict__ cnt,
                            int* __restrict__ offs,
                            int* __restrict__ cursor) {
  if (threadIdx.x == 0) {
    int a = 0;
    for (int e = 0; e < NEXP; e++) { offs[e] = a; cursor[e] = a; a += cnt[e]; }
  }
}

// ---------------- slot assignment (order nondeterministic, values not) ----
__global__ void assign_kernel(const int* __restrict__ choice,
                              int* __restrict__ cursor,
                              int* __restrict__ a_row,
                              int* __restrict__ tok_list) {
  int t = blockIdx.x * blockDim.x + threadIdx.x;
  if (t >= NTOK) return;
  #pragma unroll
  for (int k = 0; k < 2; k++) {
    int e = choice[2 * t + k];
    if (e < NEXP) {
      int pos = atomicAdd(&cursor[e], 1);
      a_row[2 * t + k] = pos;
      tok_list[pos] = t;
    } else {
      a_row[2 * t + k] = -1;
    }
  }
}

// ---------------- grouped GEMM, dbuf 2-phase, BMx128 tile, BK=32 ---------
// 1D grid, id&7 = expert (XCD pinning). Stage next tile BEFORE compute so
// the barrier's vmcnt(0) drain lands after MFMA (T3 minimum 2-phase).
template <int BM, int NDIM, int KDIM, bool SILU, bool AGATHER>
__launch_bounds__(256)
__global__ void ffn_gemm(const unsigned short* __restrict__ Abf,
                         const unsigned short* __restrict__ Bw,
                         const int* __restrict__ cnt,
                         const int* __restrict__ offs,
                         const int* __restrict__ tok_list,
                         unsigned short* __restrict__ OutBf,
                         float* __restrict__ OutF) {
  constexpr int MB = MAXA / BM;          // worst-case m-blocks per expert
  constexpr int MI = BM / 32;            // m-frags per wave
  constexpr int AJ = BM / 64;            // A staging issues (64 rows each)
  int id = blockIdx.x;
  int e  = id & 7;
  int r  = id >> 3;
  int mb = r % MB;
  int nb = r / MB;
  int count = cnt[e];
  int m0 = mb * BM;
  if (m0 >= count) return;
  int off = offs[e];
  int n0 = nb * 128;
  const unsigned short* B = Bw + (size_t)e * NDIM * KDIM;

  __shared__ unsigned short lA[2][BM * 32];
  __shared__ unsigned short lB[2][128 * 32];

  int tid  = threadIdx.x;
  int lane = tid & 63;
  int wv = tid >> 6;
  int wm = wv >> 1, wn = wv & 1;
  int lr = lane & 15, lk8 = (lane >> 4) * 8;

  // staging: issue j covers rows [j*64, j*64+64); thread -> row tid>>2, col (tid&3)*8
  int srow = tid >> 2;
  int scol = (tid & 3) * 8;
  const unsigned short* aSrc[AJ];
  const unsigned short* bSrc[2];
  #pragma unroll
  for (int j = 0; j < AJ; j++) {
    int rr = m0 + j * 64 + srow;
    if (rr >= count) rr = count - 1;
    if (AGATHER) aSrc[j] = Abf + (size_t)tok_list[off + rr] * KDIM + scol;
    else         aSrc[j] = Abf + (size_t)(off + rr) * KDIM + scol;
  }
  #pragma unroll
  for (int j = 0; j < 2; j++)
    bSrc[j] = B + (size_t)(n0 + j * 64 + srow) * KDIM + scol;

  f32x4 acc[MI][4] = {};

#define STAGE(b, kk)                                                        \
  do {                                                                      \
    int kb_ = (kk) * 32;                                                    \
    _Pragma("unroll")                                                       \
    for (int j = 0; j < AJ; j++) G2L16(aSrc[j] + kb_, &lA[b][j * 2048 + tid * 8]); \
    _Pragma("unroll")                                                       \
    for (int j = 0; j < 2; j++)  G2L16(bSrc[j] + kb_, &lB[b][j * 2048 + tid * 8]); \
  } while (0)

#define COMPUTE(b)                                                          \
  do {                                                                      \
    bf16x8 af[MI], bq[4];                                                   \
    _Pragma("unroll")                                                       \
    for (int mi = 0; mi < MI; mi++)                                         \
      af[mi] = *(const bf16x8*)&lA[b][(wm * (BM / 2) + mi * 16 + lr) * 32 + lk8]; \
    _Pragma("unroll")                                                       \
    for (int ni = 0; ni < 4; ni++)                                          \
      bq[ni] = *(const bf16x8*)&lB[b][(wn * 64 + ni * 16 + lr) * 32 + lk8]; \
    _Pragma("unroll")                                                       \
    for (int mi = 0; mi < MI; mi++)                                         \
      _Pragma("unroll")                                                     \
      for (int ni = 0; ni < 4; ni++)                                        \
        acc[mi][ni] = __builtin_amdgcn_mfma_f32_16x16x32_bf16(af[mi], bq[ni], acc[mi][ni], 0, 0, 0); \
  } while (0)

  constexpr int NK = KDIM / 32;   // even
  STAGE(0, 0);
  __syncthreads();
  #pragma unroll 1
  for (int kk = 0; kk < NK; kk += 2) {
    if (kk + 1 < NK) STAGE(1, kk + 1);
    COMPUTE(0);
    __syncthreads();
    if (kk + 1 < NK) {
      if (kk + 2 < NK) STAGE(0, kk + 2);
      COMPUTE(1);
      __syncthreads();
    }
  }
#undef STAGE
#undef COMPUTE

  // epilogue: C/D layout col=lane&15, row=(lane>>4)*4+i  [m89-verified]
  int rb = (lane >> 4) * 4;
  #pragma unroll
  for (int mi = 0; mi < MI; mi++) {
    #pragma unroll
    for (int i = 0; i < 4; i++) {
      int grow = m0 + wm * (BM / 2) + mi * 16 + rb + i;
      if (grow >= count) continue;
      #pragma unroll
      for (int ni = 0; ni < 4; ni++) {
        int gcol = n0 + wn * 64 + ni * 16 + lr;
        float v = acc[mi][ni][i];
        if (SILU) {
          float s = v / (1.f + expf(-v));
          OutBf[(size_t)(off + grow) * NDIM + gcol] = f2bf(s);
        } else {
          OutF[(size_t)(off + grow) * NDIM + gcol] = v;
        }
      }
    }
  }
}

// ---------------- final combine: out = wz*x + sum_k w_k * Y[row_k] --------
__global__ void combine_kernel(const float* __restrict__ x,
                               const float* __restrict__ Y,
                               const int* __restrict__ a_row,
                               const float* __restrict__ chw,
                               const float* __restrict__ wz,
                               float* __restrict__ out) {
  int t = blockIdx.x;
  int d = threadIdx.x * 4;
  const float4 xv = *(const float4*)&x[(size_t)t * DMODEL + d];
  float z = wz[t];
  float4 o; o.x = z * xv.x; o.y = z * xv.y; o.z = z * xv.z; o.w = z * xv.w;
  #pragma unroll
  for (int k = 0; k < 2; k++) {
    int r = a_row[2 * t + k];
    if (r >= 0) {
      float w = chw[2 * t + k];
      const float4 yv = *(const float4*)&Y[(size_t)r * DMODEL + d];
      o.x += w * yv.x; o.y += w * yv.y; o.z += w * yv.z; o.w += w * yv.w;
    }
  }
  *(float4*)&out[(size_t)t * DMODEL + d] = o;
}

extern "C" void kernel_launch(void* const* d_in, const int* in_sizes, int n_in,
                              void* d_out, int out_size, void* d_ws, size_t ws_size,
                              hipStream_t stream) {
  const float* x  = (const float*)d_in[0];   // (2,2048,1024)
  const float* gw = (const float*)d_in[1];   // (12,1024)
  const float* eb = (const float*)d_in[2];   // (12,)
  const float* w1 = (const float*)d_in[3];   // (8,2048,1024)
  const float* w2 = (const float*)d_in[4];   // (8,1024,2048)
  float* out = (float*)d_out;

  char* ws = (char*)d_ws;
  size_t o = 0;
  int*   cnt     = (int*)(ws + o);  o += 8 * sizeof(int);
  int*   offs    = (int*)(ws + o);  o += 8 * sizeof(int);
  int*   cursor  = (int*)(ws + o);  o += 8 * sizeof(int);
  o = (o + 255) & ~(size_t)255;
  int*   choice  = (int*)(ws + o);  o += (size_t)2 * NTOK * sizeof(int);
  float* chw     = (float*)(ws + o); o += (size_t)2 * NTOK * sizeof(float);
  float* wzv     = (float*)(ws + o); o += (size_t)NTOK * sizeof(float);
  int*   a_row   = (int*)(ws + o);  o += (size_t)2 * NTOK * sizeof(int);
  int*   tok     = (int*)(ws + o);  o += (size_t)MAXA * sizeof(int);
  o = (o + 255) & ~(size_t)255;
  unsigned short* Xb  = (unsigned short*)(ws + o); o += (size_t)NTOK * DMODEL * sizeof(unsigned short);
  unsigned short* W1b = (unsigned short*)(ws + o); o += (size_t)NEXP * DFFN * DMODEL * sizeof(unsigned short);
  unsigned short* W2b = (unsigned short*)(ws + o); o += (size_t)NEXP * DMODEL * DFFN * sizeof(unsigned short);
  unsigned short* H   = (unsigned short*)(ws + o); o += (size_t)MAXA * DFFN * sizeof(unsigned short);
  // Y aliases W1b (33.55 MB each): W1b is dead after GEMM1, GEMM2 reads only H+W2b.
  float* Y = (float*)W1b;

  hipMemsetAsync(cnt, 0, 8 * sizeof(int), stream);

  cvt_bf16_kernel<<<dim3(2048), dim3(256), 0, stream>>>(w1, W1b, (NEXP * DFFN * DMODEL) / 8);
  cvt_bf16_kernel<<<dim3(2048), dim3(256), 0, stream>>>(w2, W2b, (NEXP * DMODEL * DFFN) / 8);
  cvt_bf16_kernel<<<dim3(1024), dim3(256), 0, stream>>>(x, Xb, (NTOK * DMODEL) / 8);

  route_kernel<<<dim3((NTOK * 64) / 256), dim3(256), 0, stream>>>(x, gw, eb, cnt, choice, chw, wzv);
  scan_kernel<<<dim3(1), dim3(64), 0, stream>>>(cnt, offs, cursor);
  assign_kernel<<<dim3(NTOK / 256), dim3(256), 0, stream>>>(choice, cursor, a_row, tok);

  // GEMM1: H = silu(Xb @ W1b^T)   M<=cnt[e], N=2048, K=1024; BM=128
  ffn_gemm<128, DFFN, DMODEL, true, true>
      <<<dim3(NEXP * (MAXA / 128) * (DFFN / 128)), dim3(256), 0, stream>>>(
      Xb, W1b, cnt, offs, tok, H, nullptr);
  // GEMM2: Y = H @ W2b^T          M<=cnt[e], N=1024, K=2048; BM=64
  ffn_gemm<64, DMODEL, DFFN, false, false>
      <<<dim3(NEXP * (MAXA / 64) * (DMODEL / 128)), dim3(256), 0, stream>>>(
      H, W2b, cnt, offs, tok, nullptr, Y);

  combine_kernel<<<dim3(NTOK), dim3(256), 0, stream>>>(x, Y, a_row, chw, wzv, out);
}

// Round 5
// 223.043 us; speedup vs baseline: 2.3765x; 1.1807x over previous
//
#include <hip/hip_runtime.h>
#include <math.h>

#define NTOK   4096      // B*S
#define DMODEL 1024
#define DFFN   2048
#define NEXP   8         // FFN experts
#define ETOT   12        // total experts (8 FFN + 4 zero)
#define MAXA   8192      // max assignments (NTOK * TOP_K)

typedef short  bf16x8 __attribute__((ext_vector_type(8)));
typedef float  f32x4  __attribute__((ext_vector_type(4)));

__device__ __forceinline__ unsigned short f2bf(float f) {
  unsigned int u = __float_as_uint(f);
  unsigned int r = (u + 0x7fffu + ((u >> 16) & 1u)) >> 16;  // RNE
  return (unsigned short)r;
}

#define G2L16(g, l)                                                        \
  __builtin_amdgcn_global_load_lds(                                        \
      (const __attribute__((address_space(1))) void*)(g),                  \
      (__attribute__((address_space(3))) void*)(l), 16, 0, 0)

// ---------------- fp32 -> bf16 bulk convert (grid-stride, 8 elems/thr) ----
__global__ void cvt_bf16_kernel(const float* __restrict__ in,
                                unsigned short* __restrict__ outp, int n8) {
  for (int i = blockIdx.x * blockDim.x + threadIdx.x; i < n8;
       i += gridDim.x * blockDim.x) {
    const float4* p = (const float4*)in;
    float4 v0 = p[2 * i], v1 = p[2 * i + 1];
    ushort4 u0, u1;
    u0.x = f2bf(v0.x); u0.y = f2bf(v0.y); u0.z = f2bf(v0.z); u0.w = f2bf(v0.w);
    u1.x = f2bf(v1.x); u1.y = f2bf(v1.y); u1.z = f2bf(v1.z); u1.w = f2bf(v1.w);
    ((ushort4*)outp)[2 * i]     = u0;
    ((ushort4*)outp)[2 * i + 1] = u1;
  }
}

// ---------------- routing phase A: logits = x @ gw^T + eb (fp32) ---------
// 16 tokens/block, 16 lanes/token; gw staged in LDS (48 KB).
__launch_bounds__(256)
__global__ void logits_kernel(const float* __restrict__ x,
                              const float* __restrict__ gw,
                              const float* __restrict__ eb,
                              float* __restrict__ logits) {
  __shared__ float gws[ETOT * DMODEL];   // 48 KB
  int tid = threadIdx.x;
  const float4* gw4 = (const float4*)gw;
  float4* gws4 = (float4*)gws;
  #pragma unroll
  for (int i = 0; i < (ETOT * DMODEL / 4) / 256; i++)
    gws4[tid + i * 256] = gw4[tid + i * 256];
  __syncthreads();

  int sub = tid >> 4;         // token within block (0..15)
  int l16 = tid & 15;         // lane within token group
  int tok = blockIdx.x * 16 + sub;
  const float4* xr = (const float4*)(x + (size_t)tok * DMODEL);

  float s[ETOT] = {};
  #pragma unroll
  for (int j = 0; j < 16; j++) {
    float4 xv = xr[l16 + j * 16];
    #pragma unroll
    for (int e = 0; e < ETOT; e++) {
      float4 g = gws4[e * (DMODEL / 4) + l16 + j * 16];
      s[e] += xv.x * g.x + xv.y * g.y + xv.z * g.z + xv.w * g.w;
    }
  }
  // reduce across the 16-lane group (xor masks stay within group)
  #pragma unroll
  for (int e = 0; e < ETOT; e++) {
    #pragma unroll
    for (int m = 8; m >= 1; m >>= 1) s[e] += __shfl_xor(s[e], m, 64);
  }
  if (l16 == 0) {
    #pragma unroll
    for (int e = 0; e < ETOT; e++)
      logits[(size_t)tok * ETOT + e] = s[e] + eb[e];
  }
}

// ---------------- routing phase B: top-2, softmax, counts ----------------
__global__ void topk_kernel(const float* __restrict__ logits,
                            int* __restrict__ cnt,
                            int* __restrict__ choice,
                            float* __restrict__ chw,
                            float* __restrict__ wz) {
  int t = blockIdx.x * blockDim.x + threadIdx.x;
  if (t >= NTOK) return;
  const float4* lr = (const float4*)(logits + (size_t)t * ETOT);
  float4 a = lr[0], b = lr[1], c = lr[2];
  float lg[ETOT] = { a.x, a.y, a.z, a.w, b.x, b.y, b.z, b.w, c.x, c.y, c.z, c.w };
  // top-2, ties -> lowest index (matches jax.lax.top_k)
  int i1 = 0; float m1 = lg[0];
  #pragma unroll
  for (int e = 1; e < ETOT; e++) if (lg[e] > m1) { m1 = lg[e]; i1 = e; }
  int i2 = -1; float m2 = -3.4e38f;
  #pragma unroll
  for (int e = 0; e < ETOT; e++) { if (e == i1) continue; if (lg[e] > m2) { m2 = lg[e]; i2 = e; } }
  float ex = expf(m2 - m1);
  float w0 = 1.f / (1.f + ex);
  float w1 = ex / (1.f + ex);
  int ee[2] = { i1, i2 };
  float ww[2] = { w0, w1 };
  float z = 0.f;
  #pragma unroll
  for (int k = 0; k < 2; k++) {
    choice[t * 2 + k] = ee[k];
    chw[t * 2 + k]    = ww[k];
    if (ee[k] < NEXP) atomicAdd(&cnt[ee[k]], 1);
    else              z += ww[k];
  }
  wz[t] = z;
}

// ---------------- tiny exclusive scan over 8 counts ----------------
__global__ void scan_kernel(const int* __restrict__ cnt,
                            int* __restrict__ offs,
                            int* __restrict__ cursor) {
  if (threadIdx.x == 0) {
    int a = 0;
    for (int e = 0; e < NEXP; e++) { offs[e] = a; cursor[e] = a; a += cnt[e]; }
  }
}

// ---------------- slot assignment (order nondeterministic, values not) ----
__global__ void assign_kernel(const int* __restrict__ choice,
                              int* __restrict__ cursor,
                              int* __restrict__ a_row,
                              int* __restrict__ tok_list) {
  int t = blockIdx.x * blockDim.x + threadIdx.x;
  if (t >= NTOK) return;
  #pragma unroll
  for (int k = 0; k < 2; k++) {
    int e = choice[2 * t + k];
    if (e < NEXP) {
      int pos = atomicAdd(&cursor[e], 1);
      a_row[2 * t + k] = pos;
      tok_list[pos] = t;
    } else {
      a_row[2 * t + k] = -1;
    }
  }
}

// ---------------- grouped GEMM, dbuf 2-phase, BMx128 tile, BK=32 ---------
// 1D grid, id&7 = expert (XCD pinning). Stage next tile BEFORE compute so
// the barrier's vmcnt(0) drain lands after MFMA (T3 minimum 2-phase).
template <int BM, int NDIM, int KDIM, bool SILU, bool AGATHER>
__launch_bounds__(256)
__global__ void ffn_gemm(const unsigned short* __restrict__ Abf,
                         const unsigned short* __restrict__ Bw,
                         const int* __restrict__ cnt,
                         const int* __restrict__ offs,
                         const int* __restrict__ tok_list,
                         unsigned short* __restrict__ OutBf,
                         float* __restrict__ OutF) {
  constexpr int MB = MAXA / BM;          // worst-case m-blocks per expert
  constexpr int MI = BM / 32;            // m-frags per wave
  constexpr int AJ = BM / 64;            // A staging issues (64 rows each)
  int id = blockIdx.x;
  int e  = id & 7;
  int r  = id >> 3;
  int mb = r % MB;
  int nb = r / MB;
  int count = cnt[e];
  int m0 = mb * BM;
  if (m0 >= count) return;
  int off = offs[e];
  int n0 = nb * 128;
  const unsigned short* B = Bw + (size_t)e * NDIM * KDIM;

  __shared__ unsigned short lA[2][BM * 32];
  __shared__ unsigned short lB[2][128 * 32];

  int tid  = threadIdx.x;
  int lane = tid & 63;
  int wv = tid >> 6;
  int wm = wv >> 1, wn = wv & 1;
  int lr = lane & 15, lk8 = (lane >> 4) * 8;

  // staging: issue j covers rows [j*64, j*64+64); thread -> row tid>>2, col (tid&3)*8
  int srow = tid >> 2;
  int scol = (tid & 3) * 8;
  const unsigned short* aSrc[AJ];
  const unsigned short* bSrc[2];
  #pragma unroll
  for (int j = 0; j < AJ; j++) {
    int rr = m0 + j * 64 + srow;
    if (rr >= count) rr = count - 1;
    if (AGATHER) aSrc[j] = Abf + (size_t)tok_list[off + rr] * KDIM + scol;
    else         aSrc[j] = Abf + (size_t)(off + rr) * KDIM + scol;
  }
  #pragma unroll
  for (int j = 0; j < 2; j++)
    bSrc[j] = B + (size_t)(n0 + j * 64 + srow) * KDIM + scol;

  f32x4 acc[MI][4] = {};

#define STAGE(b, kk)                                                        \
  do {                                                                      \
    int kb_ = (kk) * 32;                                                    \
    _Pragma("unroll")                                                       \
    for (int j = 0; j < AJ; j++) G2L16(aSrc[j] + kb_, &lA[b][j * 2048 + tid * 8]); \
    _Pragma("unroll")                                                       \
    for (int j = 0; j < 2; j++)  G2L16(bSrc[j] + kb_, &lB[b][j * 2048 + tid * 8]); \
  } while (0)

#define COMPUTE(b)                                                          \
  do {                                                                      \
    bf16x8 af[MI], bq[4];                                                   \
    _Pragma("unroll")                                                       \
    for (int mi = 0; mi < MI; mi++)                                         \
      af[mi] = *(const bf16x8*)&lA[b][(wm * (BM / 2) + mi * 16 + lr) * 32 + lk8]; \
    _Pragma("unroll")                                                       \
    for (int ni = 0; ni < 4; ni++)                                          \
      bq[ni] = *(const bf16x8*)&lB[b][(wn * 64 + ni * 16 + lr) * 32 + lk8]; \
    _Pragma("unroll")                                                       \
    for (int mi = 0; mi < MI; mi++)                                         \
      _Pragma("unroll")                                                     \
      for (int ni = 0; ni < 4; ni++)                                        \
        acc[mi][ni] = __builtin_amdgcn_mfma_f32_16x16x32_bf16(af[mi], bq[ni], acc[mi][ni], 0, 0, 0); \
  } while (0)

  constexpr int NK = KDIM / 32;   // even
  STAGE(0, 0);
  __syncthreads();
  #pragma unroll 1
  for (int kk = 0; kk < NK; kk += 2) {
    if (kk + 1 < NK) STAGE(1, kk + 1);
    COMPUTE(0);
    __syncthreads();
    if (kk + 1 < NK) {
      if (kk + 2 < NK) STAGE(0, kk + 2);
      COMPUTE(1);
      __syncthreads();
    }
  }
#undef STAGE
#undef COMPUTE

  // epilogue: C/D layout col=lane&15, row=(lane>>4)*4+i  [m89-verified]
  int rb = (lane >> 4) * 4;
  #pragma unroll
  for (int mi = 0; mi < MI; mi++) {
    #pragma unroll
    for (int i = 0; i < 4; i++) {
      int grow = m0 + wm * (BM / 2) + mi * 16 + rb + i;
      if (grow >= count) continue;
      #pragma unroll
      for (int ni = 0; ni < 4; ni++) {
        int gcol = n0 + wn * 64 + ni * 16 + lr;
        float v = acc[mi][ni][i];
        if (SILU) {
          float s = v / (1.f + expf(-v));
          OutBf[(size_t)(off + grow) * NDIM + gcol] = f2bf(s);
        } else {
          OutF[(size_t)(off + grow) * NDIM + gcol] = v;
        }
      }
    }
  }
}

// ---------------- final combine: out = wz*x + sum_k w_k * Y[row_k] --------
__global__ void combine_kernel(const float* __restrict__ x,
                               const float* __restrict__ Y,
                               const int* __restrict__ a_row,
                               const float* __restrict__ chw,
                               const float* __restrict__ wz,
                               float* __restrict__ out) {
  int t = blockIdx.x;
  int d = threadIdx.x * 4;
  const float4 xv = *(const float4*)&x[(size_t)t * DMODEL + d];
  float z = wz[t];
  float4 o; o.x = z * xv.x; o.y = z * xv.y; o.z = z * xv.z; o.w = z * xv.w;
  #pragma unroll
  for (int k = 0; k < 2; k++) {
    int r = a_row[2 * t + k];
    if (r >= 0) {
      float w = chw[2 * t + k];
      const float4 yv = *(const float4*)&Y[(size_t)r * DMODEL + d];
      o.x += w * yv.x; o.y += w * yv.y; o.z += w * yv.z; o.w += w * yv.w;
    }
  }
  *(float4*)&out[(size_t)t * DMODEL + d] = o;
}

extern "C" void kernel_launch(void* const* d_in, const int* in_sizes, int n_in,
                              void* d_out, int out_size, void* d_ws, size_t ws_size,
                              hipStream_t stream) {
  const float* x  = (const float*)d_in[0];   // (2,2048,1024)
  const float* gw = (const float*)d_in[1];   // (12,1024)
  const float* eb = (const float*)d_in[2];   // (12,)
  const float* w1 = (const float*)d_in[3];   // (8,2048,1024)
  const float* w2 = (const float*)d_in[4];   // (8,1024,2048)
  float* out = (float*)d_out;

  char* ws = (char*)d_ws;
  size_t o = 0;
  int*   cnt     = (int*)(ws + o);  o += 8 * sizeof(int);
  int*   offs    = (int*)(ws + o);  o += 8 * sizeof(int);
  int*   cursor  = (int*)(ws + o);  o += 8 * sizeof(int);
  o = (o + 255) & ~(size_t)255;
  int*   choice  = (int*)(ws + o);  o += (size_t)2 * NTOK * sizeof(int);
  float* chw     = (float*)(ws + o); o += (size_t)2 * NTOK * sizeof(float);
  float* wzv     = (float*)(ws + o); o += (size_t)NTOK * sizeof(float);
  int*   a_row   = (int*)(ws + o);  o += (size_t)2 * NTOK * sizeof(int);
  int*   tok     = (int*)(ws + o);  o += (size_t)MAXA * sizeof(int);
  float* logits  = (float*)(ws + o); o += (size_t)NTOK * ETOT * sizeof(float);
  o = (o + 255) & ~(size_t)255;
  unsigned short* Xb  = (unsigned short*)(ws + o); o += (size_t)NTOK * DMODEL * sizeof(unsigned short);
  unsigned short* W1b = (unsigned short*)(ws + o); o += (size_t)NEXP * DFFN * DMODEL * sizeof(unsigned short);
  unsigned short* W2b = (unsigned short*)(ws + o); o += (size_t)NEXP * DMODEL * DFFN * sizeof(unsigned short);
  unsigned short* H   = (unsigned short*)(ws + o); o += (size_t)MAXA * DFFN * sizeof(unsigned short);
  // Y aliases W1b (33.55 MB each): W1b is dead after GEMM1, GEMM2 reads only H+W2b.
  float* Y = (float*)W1b;

  hipMemsetAsync(cnt, 0, 8 * sizeof(int), stream);

  cvt_bf16_kernel<<<dim3(2048), dim3(256), 0, stream>>>(w1, W1b, (NEXP * DFFN * DMODEL) / 8);
  cvt_bf16_kernel<<<dim3(2048), dim3(256), 0, stream>>>(w2, W2b, (NEXP * DMODEL * DFFN) / 8);
  cvt_bf16_kernel<<<dim3(1024), dim3(256), 0, stream>>>(x, Xb, (NTOK * DMODEL) / 8);

  logits_kernel<<<dim3(NTOK / 16), dim3(256), 0, stream>>>(x, gw, eb, logits);
  topk_kernel<<<dim3(NTOK / 256), dim3(256), 0, stream>>>(logits, cnt, choice, chw, wzv);
  scan_kernel<<<dim3(1), dim3(64), 0, stream>>>(cnt, offs, cursor);
  assign_kernel<<<dim3(NTOK / 256), dim3(256), 0, stream>>>(choice, cursor, a_row, tok);

  // GEMM1: H = silu(Xb @ W1b^T)   M<=cnt[e], N=2048, K=1024; BM=128
  ffn_gemm<128, DFFN, DMODEL, true, true>
      <<<dim3(NEXP * (MAXA / 128) * (DFFN / 128)), dim3(256), 0, stream>>>(
      Xb, W1b, cnt, offs, tok, H, nullptr);
  // GEMM2: Y = H @ W2b^T          M<=cnt[e], N=1024, K=2048; BM=64
  ffn_gemm<64, DMODEL, DFFN, false, false>
      <<<dim3(NEXP * (MAXA / 64) * (DMODEL / 128)), dim3(256), 0, stream>>>(
      H, W2b, cnt, offs, tok, nullptr, Y);

  combine_kernel<<<dim3(NTOK), dim3(256), 0, stream>>>(x, Y, a_row, chw, wzv, out);
}

// Round 6
// 199.387 us; speedup vs baseline: 2.6585x; 1.1186x over previous
//
#include <hip/hip_runtime.h>
#include <math.h>

#define NTOK   4096      // B*S
#define DMODEL 1024
#define DFFN   2048
#define NEXP   8         // FFN experts
#define ETOT   12        // total experts (8 FFN + 4 zero)
#define MAXA   8192      // max assignments (NTOK * TOP_K)
#define WL1MAX (MAXA / 128 + NEXP)   // 72  worst-case m-blocks, BM=128
#define WL2MAX (MAXA / 64  + NEXP)   // 136 worst-case m-blocks, BM=64

typedef short  bf16x8 __attribute__((ext_vector_type(8)));
typedef float  f32x4  __attribute__((ext_vector_type(4)));

__device__ __forceinline__ unsigned short f2bf(float f) {
  unsigned int u = __float_as_uint(f);
  unsigned int r = (u + 0x7fffu + ((u >> 16) & 1u)) >> 16;  // RNE
  return (unsigned short)r;
}

#define G2L16(g, l)                                                        \
  __builtin_amdgcn_global_load_lds(                                        \
      (const __attribute__((address_space(1))) void*)(g),                  \
      (__attribute__((address_space(3))) void*)(l), 16, 0, 0)

// ---------------- fp32 -> bf16 bulk convert (grid-stride, 8 elems/thr) ----
__global__ void cvt_bf16_kernel(const float* __restrict__ in,
                                unsigned short* __restrict__ outp, int n8) {
  for (int i = blockIdx.x * blockDim.x + threadIdx.x; i < n8;
       i += gridDim.x * blockDim.x) {
    const float4* p = (const float4*)in;
    float4 v0 = p[2 * i], v1 = p[2 * i + 1];
    ushort4 u0, u1;
    u0.x = f2bf(v0.x); u0.y = f2bf(v0.y); u0.z = f2bf(v0.z); u0.w = f2bf(v0.w);
    u1.x = f2bf(v1.x); u1.y = f2bf(v1.y); u1.z = f2bf(v1.z); u1.w = f2bf(v1.w);
    ((ushort4*)outp)[2 * i]     = u0;
    ((ushort4*)outp)[2 * i + 1] = u1;
  }
}

// ---------------- routing phase A: logits = x @ gw^T + eb (fp32) ---------
__launch_bounds__(256)
__global__ void logits_kernel(const float* __restrict__ x,
                              const float* __restrict__ gw,
                              const float* __restrict__ eb,
                              float* __restrict__ logits) {
  __shared__ float gws[ETOT * DMODEL];   // 48 KB
  int tid = threadIdx.x;
  const float4* gw4 = (const float4*)gw;
  float4* gws4 = (float4*)gws;
  #pragma unroll
  for (int i = 0; i < (ETOT * DMODEL / 4) / 256; i++)
    gws4[tid + i * 256] = gw4[tid + i * 256];
  __syncthreads();

  int sub = tid >> 4;
  int l16 = tid & 15;
  int tok = blockIdx.x * 16 + sub;
  const float4* xr = (const float4*)(x + (size_t)tok * DMODEL);

  float s[ETOT] = {};
  #pragma unroll
  for (int j = 0; j < 16; j++) {
    float4 xv = xr[l16 + j * 16];
    #pragma unroll
    for (int e = 0; e < ETOT; e++) {
      float4 g = gws4[e * (DMODEL / 4) + l16 + j * 16];
      s[e] += xv.x * g.x + xv.y * g.y + xv.z * g.z + xv.w * g.w;
    }
  }
  #pragma unroll
  for (int e = 0; e < ETOT; e++) {
    #pragma unroll
    for (int m = 8; m >= 1; m >>= 1) s[e] += __shfl_xor(s[e], m, 64);
  }
  if (l16 == 0) {
    #pragma unroll
    for (int e = 0; e < ETOT; e++)
      logits[(size_t)tok * ETOT + e] = s[e] + eb[e];
  }
}

// ---------------- routing phase B: top-2, softmax, counts ----------------
__global__ void topk_kernel(const float* __restrict__ logits,
                            int* __restrict__ cnt,
                            int* __restrict__ choice,
                            float* __restrict__ chw,
                            float* __restrict__ wz) {
  int t = blockIdx.x * blockDim.x + threadIdx.x;
  if (t >= NTOK) return;
  const float4* lr = (const float4*)(logits + (size_t)t * ETOT);
  float4 a = lr[0], b = lr[1], c = lr[2];
  float lg[ETOT] = { a.x, a.y, a.z, a.w, b.x, b.y, b.z, b.w, c.x, c.y, c.z, c.w };
  int i1 = 0; float m1 = lg[0];
  #pragma unroll
  for (int e = 1; e < ETOT; e++) if (lg[e] > m1) { m1 = lg[e]; i1 = e; }
  int i2 = -1; float m2 = -3.4e38f;
  #pragma unroll
  for (int e = 0; e < ETOT; e++) { if (e == i1) continue; if (lg[e] > m2) { m2 = lg[e]; i2 = e; } }
  float ex = expf(m2 - m1);
  float w0 = 1.f / (1.f + ex);
  float w1 = ex / (1.f + ex);
  int ee[2] = { i1, i2 };
  float ww[2] = { w0, w1 };
  float z = 0.f;
  #pragma unroll
  for (int k = 0; k < 2; k++) {
    choice[t * 2 + k] = ee[k];
    chw[t * 2 + k]    = ww[k];
    if (ee[k] < NEXP) atomicAdd(&cnt[ee[k]], 1);
    else              z += ww[k];
  }
  wz[t] = z;
}

// -------- scan + dense worklists: (expert|mb<<8) per working m-block ------
__global__ void scan_kernel(const int* __restrict__ cnt,
                            int* __restrict__ offs,
                            int* __restrict__ cursor,
                            int* __restrict__ wl1, int* __restrict__ nw1,
                            int* __restrict__ wl2, int* __restrict__ nw2) {
  if (threadIdx.x == 0) {
    int a = 0;
    for (int e = 0; e < NEXP; e++) { offs[e] = a; cursor[e] = a; a += cnt[e]; }
    int n1 = 0, n2 = 0;
    for (int e = 0; e < NEXP; e++) {
      int c = cnt[e];
      for (int mb = 0; mb * 128 < c; mb++) wl1[n1++] = e | (mb << 8);
      for (int mb = 0; mb * 64  < c; mb++) wl2[n2++] = e | (mb << 8);
    }
    *nw1 = n1; *nw2 = n2;
  }
}

// ---------------- slot assignment (order nondeterministic, values not) ----
__global__ void assign_kernel(const int* __restrict__ choice,
                              int* __restrict__ cursor,
                              int* __restrict__ a_row,
                              int* __restrict__ tok_list) {
  int t = blockIdx.x * blockDim.x + threadIdx.x;
  if (t >= NTOK) return;
  #pragma unroll
  for (int k = 0; k < 2; k++) {
    int e = choice[2 * t + k];
    if (e < NEXP) {
      int pos = atomicAdd(&cursor[e], 1);
      a_row[2 * t + k] = pos;
      tok_list[pos] = t;
    } else {
      a_row[2 * t + k] = -1;
    }
  }
}

// ---------------- grouped GEMM, dbuf 2-phase, BMx128 tile, BK=32 ---------
// Dense worklist: block id = wb*NB + nb; wb indexes wl (packed e|mb<<8).
// All working blocks are contiguous ids [0, nwork*NB) -> dense residency.
template <int BM, int NDIM, int KDIM, bool SILU, bool AGATHER>
__launch_bounds__(256)
__global__ void ffn_gemm(const unsigned short* __restrict__ Abf,
                         const unsigned short* __restrict__ Bw,
                         const int* __restrict__ cnt,
                         const int* __restrict__ offs,
                         const int* __restrict__ tok_list,
                         const int* __restrict__ wl,
                         const int* __restrict__ nwork,
                         unsigned short* __restrict__ OutBf,
                         float* __restrict__ OutF) {
  constexpr int NB = NDIM / 128;         // n-blocks (power of 2)
  constexpr int MI = BM / 32;            // m-frags per wave
  constexpr int AJ = BM / 64;            // A staging issues (64 rows each)
  int id = blockIdx.x;
  int nb = id & (NB - 1);
  int wb = id / NB;
  if (wb >= *nwork) return;
  int w  = wl[wb];
  int e  = w & 255;
  int mb = w >> 8;
  int count = cnt[e];
  int m0 = mb * BM;
  int off = offs[e];
  int n0 = nb * 128;
  const unsigned short* B = Bw + (size_t)e * NDIM * KDIM;

  __shared__ unsigned short lA[2][BM * 32];
  __shared__ unsigned short lB[2][128 * 32];

  int tid  = threadIdx.x;
  int lane = tid & 63;
  int wv = tid >> 6;
  int wm = wv >> 1, wn = wv & 1;
  int lr = lane & 15, lk8 = (lane >> 4) * 8;

  int srow = tid >> 2;
  int scol = (tid & 3) * 8;
  const unsigned short* aSrc[AJ];
  const unsigned short* bSrc[2];
  #pragma unroll
  for (int j = 0; j < AJ; j++) {
    int rr = m0 + j * 64 + srow;
    if (rr >= count) rr = count - 1;
    if (AGATHER) aSrc[j] = Abf + (size_t)tok_list[off + rr] * KDIM + scol;
    else         aSrc[j] = Abf + (size_t)(off + rr) * KDIM + scol;
  }
  #pragma unroll
  for (int j = 0; j < 2; j++)
    bSrc[j] = B + (size_t)(n0 + j * 64 + srow) * KDIM + scol;

  f32x4 acc[MI][4] = {};

#define STAGE(b, kk)                                                        \
  do {                                                                      \
    int kb_ = (kk) * 32;                                                    \
    _Pragma("unroll")                                                       \
    for (int j = 0; j < AJ; j++) G2L16(aSrc[j] + kb_, &lA[b][j * 2048 + tid * 8]); \
    _Pragma("unroll")                                                       \
    for (int j = 0; j < 2; j++)  G2L16(bSrc[j] + kb_, &lB[b][j * 2048 + tid * 8]); \
  } while (0)

#define COMPUTE(b)                                                          \
  do {                                                                      \
    bf16x8 af[MI], bq[4];                                                   \
    _Pragma("unroll")                                                       \
    for (int mi = 0; mi < MI; mi++)                                         \
      af[mi] = *(const bf16x8*)&lA[b][(wm * (BM / 2) + mi * 16 + lr) * 32 + lk8]; \
    _Pragma("unroll")                                                       \
    for (int ni = 0; ni < 4; ni++)                                          \
      bq[ni] = *(const bf16x8*)&lB[b][(wn * 64 + ni * 16 + lr) * 32 + lk8]; \
    _Pragma("unroll")                                                       \
    for (int mi = 0; mi < MI; mi++)                                         \
      _Pragma("unroll")                                                     \
      for (int ni = 0; ni < 4; ni++)                                        \
        acc[mi][ni] = __builtin_amdgcn_mfma_f32_16x16x32_bf16(af[mi], bq[ni], acc[mi][ni], 0, 0, 0); \
  } while (0)

  constexpr int NK = KDIM / 32;   // even
  STAGE(0, 0);
  __syncthreads();
  #pragma unroll 1
  for (int kk = 0; kk < NK; kk += 2) {
    if (kk + 1 < NK) STAGE(1, kk + 1);
    COMPUTE(0);
    __syncthreads();
    if (kk + 1 < NK) {
      if (kk + 2 < NK) STAGE(0, kk + 2);
      COMPUTE(1);
      __syncthreads();
    }
  }
#undef STAGE
#undef COMPUTE

  // epilogue: C/D layout col=lane&15, row=(lane>>4)*4+i  [m89-verified]
  int rb = (lane >> 4) * 4;
  #pragma unroll
  for (int mi = 0; mi < MI; mi++) {
    #pragma unroll
    for (int i = 0; i < 4; i++) {
      int grow = m0 + wm * (BM / 2) + mi * 16 + rb + i;
      if (grow >= count) continue;
      #pragma unroll
      for (int ni = 0; ni < 4; ni++) {
        int gcol = n0 + wn * 64 + ni * 16 + lr;
        float v = acc[mi][ni][i];
        if (SILU) {
          // silu(v) = v * rcp(1 + exp2(-v*log2e)) — fast HW transcendentals
          float s = v * __builtin_amdgcn_rcpf(
                        1.f + __builtin_amdgcn_exp2f(-v * 1.44269504088896f));
          OutBf[(size_t)(off + grow) * NDIM + gcol] = f2bf(s);
        } else {
          OutF[(size_t)(off + grow) * NDIM + gcol] = v;
        }
      }
    }
  }
}

// ---------------- final combine: out = wz*x + sum_k w_k * Y[row_k] --------
__global__ void combine_kernel(const float* __restrict__ x,
                               const float* __restrict__ Y,
                               const int* __restrict__ a_row,
                               const float* __restrict__ chw,
                               const float* __restrict__ wz,
                               float* __restrict__ out) {
  int t = blockIdx.x;
  int d = threadIdx.x * 4;
  const float4 xv = *(const float4*)&x[(size_t)t * DMODEL + d];
  float z = wz[t];
  float4 o; o.x = z * xv.x; o.y = z * xv.y; o.z = z * xv.z; o.w = z * xv.w;
  #pragma unroll
  for (int k = 0; k < 2; k++) {
    int r = a_row[2 * t + k];
    if (r >= 0) {
      float w = chw[2 * t + k];
      const float4 yv = *(const float4*)&Y[(size_t)r * DMODEL + d];
      o.x += w * yv.x; o.y += w * yv.y; o.z += w * yv.z; o.w += w * yv.w;
    }
  }
  *(float4*)&out[(size_t)t * DMODEL + d] = o;
}

extern "C" void kernel_launch(void* const* d_in, const int* in_sizes, int n_in,
                              void* d_out, int out_size, void* d_ws, size_t ws_size,
                              hipStream_t stream) {
  const float* x  = (const float*)d_in[0];   // (2,2048,1024)
  const float* gw = (const float*)d_in[1];   // (12,1024)
  const float* eb = (const float*)d_in[2];   // (12,)
  const float* w1 = (const float*)d_in[3];   // (8,2048,1024)
  const float* w2 = (const float*)d_in[4];   // (8,1024,2048)
  float* out = (float*)d_out;

  char* ws = (char*)d_ws;
  size_t o = 0;
  int*   cnt     = (int*)(ws + o);  o += 8 * sizeof(int);
  int*   offs    = (int*)(ws + o);  o += 8 * sizeof(int);
  int*   cursor  = (int*)(ws + o);  o += 8 * sizeof(int);
  int*   nw1     = (int*)(ws + o);  o += sizeof(int);
  int*   nw2     = (int*)(ws + o);  o += sizeof(int);
  o = (o + 255) & ~(size_t)255;
  int*   wl1     = (int*)(ws + o);  o += WL1MAX * sizeof(int);
  int*   wl2     = (int*)(ws + o);  o += WL2MAX * sizeof(int);
  o = (o + 255) & ~(size_t)255;
  int*   choice  = (int*)(ws + o);  o += (size_t)2 * NTOK * sizeof(int);
  float* chw     = (float*)(ws + o); o += (size_t)2 * NTOK * sizeof(float);
  float* wzv     = (float*)(ws + o); o += (size_t)NTOK * sizeof(float);
  int*   a_row   = (int*)(ws + o);  o += (size_t)2 * NTOK * sizeof(int);
  int*   tok     = (int*)(ws + o);  o += (size_t)MAXA * sizeof(int);
  float* logits  = (float*)(ws + o); o += (size_t)NTOK * ETOT * sizeof(float);
  o = (o + 255) & ~(size_t)255;
  unsigned short* Xb  = (unsigned short*)(ws + o); o += (size_t)NTOK * DMODEL * sizeof(unsigned short);
  unsigned short* W1b = (unsigned short*)(ws + o); o += (size_t)NEXP * DFFN * DMODEL * sizeof(unsigned short);
  unsigned short* W2b = (unsigned short*)(ws + o); o += (size_t)NEXP * DMODEL * DFFN * sizeof(unsigned short);
  unsigned short* H   = (unsigned short*)(ws + o); o += (size_t)MAXA * DFFN * sizeof(unsigned short);
  // Y aliases W1b (33.55 MB each): W1b is dead after GEMM1, GEMM2 reads only H+W2b.
  float* Y = (float*)W1b;

  hipMemsetAsync(cnt, 0, 8 * sizeof(int), stream);

  cvt_bf16_kernel<<<dim3(2048), dim3(256), 0, stream>>>(w1, W1b, (NEXP * DFFN * DMODEL) / 8);
  cvt_bf16_kernel<<<dim3(2048), dim3(256), 0, stream>>>(w2, W2b, (NEXP * DMODEL * DFFN) / 8);
  cvt_bf16_kernel<<<dim3(1024), dim3(256), 0, stream>>>(x, Xb, (NTOK * DMODEL) / 8);

  logits_kernel<<<dim3(NTOK / 16), dim3(256), 0, stream>>>(x, gw, eb, logits);
  topk_kernel<<<dim3(NTOK / 256), dim3(256), 0, stream>>>(logits, cnt, choice, chw, wzv);
  scan_kernel<<<dim3(1), dim3(64), 0, stream>>>(cnt, offs, cursor, wl1, nw1, wl2, nw2);
  assign_kernel<<<dim3(NTOK / 256), dim3(256), 0, stream>>>(choice, cursor, a_row, tok);

  // GEMM1: H = silu(Xb @ W1b^T)   M<=cnt[e], N=2048, K=1024; BM=128
  ffn_gemm<128, DFFN, DMODEL, true, true>
      <<<dim3(WL1MAX * (DFFN / 128)), dim3(256), 0, stream>>>(
      Xb, W1b, cnt, offs, tok, wl1, nw1, H, nullptr);
  // GEMM2: Y = H @ W2b^T          M<=cnt[e], N=1024, K=2048; BM=64
  ffn_gemm<64, DMODEL, DFFN, false, false>
      <<<dim3(WL2MAX * (DMODEL / 128)), dim3(256), 0, stream>>>(
      H, W2b, cnt, offs, tok, wl2, nw2, nullptr, Y);

  combine_kernel<<<dim3(NTOK), dim3(256), 0, stream>>>(x, Y, a_row, chw, wzv, out);
}

// Round 8
// 196.612 us; speedup vs baseline: 2.6960x; 1.0141x over previous
//
#include <hip/hip_runtime.h>
#include <math.h>

#define NTOK   4096      // B*S
#define DMODEL 1024
#define DFFN   2048
#define NEXP   8         // FFN experts
#define ETOT   12        // total experts (8 FFN + 4 zero)
#define MAXA   8192      // max assignments (NTOK * TOP_K)
#define WL1MAX (MAXA / 128 + NEXP)   // 72 worst-case m-blocks, BM=128
#define WL2MAX (MAXA / 128 + NEXP)   // 72 worst-case m-blocks, BM=128

typedef short  bf16x8 __attribute__((ext_vector_type(8)));
typedef float  f32x4  __attribute__((ext_vector_type(4)));

__device__ __forceinline__ unsigned short f2bf(float f) {
  unsigned int u = __float_as_uint(f);
  unsigned int r = (u + 0x7fffu + ((u >> 16) & 1u)) >> 16;  // RNE
  return (unsigned short)r;
}

#define G2L16(g, l)                                                        \
  __builtin_amdgcn_global_load_lds(                                        \
      (const __attribute__((address_space(1))) void*)(g),                  \
      (__attribute__((address_space(3))) void*)(l), 16, 0, 0)

// ------- fused fp32 -> bf16 bulk convert of w1, w2, x (8 elems/thread) ----
__global__ void cvt3_kernel(const float* __restrict__ s0, unsigned short* __restrict__ d0, int n0,
                            const float* __restrict__ s1, unsigned short* __restrict__ d1, int n1,
                            const float* __restrict__ s2, unsigned short* __restrict__ d2, int n2) {
  int total = n0 + n1 + n2;
  for (int i = blockIdx.x * blockDim.x + threadIdx.x; i < total;
       i += gridDim.x * blockDim.x) {
    const float* src; unsigned short* dst; int j = i;
    if (j < n0)            { src = s0; dst = d0; }
    else if ((j -= n0) < n1) { src = s1; dst = d1; }
    else                   { j -= n1; src = s2; dst = d2; }
    const float4* p = (const float4*)src;
    float4 v0 = p[2 * j], v1 = p[2 * j + 1];
    ushort4 u0, u1;
    u0.x = f2bf(v0.x); u0.y = f2bf(v0.y); u0.z = f2bf(v0.z); u0.w = f2bf(v0.w);
    u1.x = f2bf(v1.x); u1.y = f2bf(v1.y); u1.z = f2bf(v1.z); u1.w = f2bf(v1.w);
    ((ushort4*)dst)[2 * j]     = u0;
    ((ushort4*)dst)[2 * j + 1] = u1;
  }
}

// ---------------- routing phase A: logits = x @ gw^T + eb (fp32) ---------
__launch_bounds__(256)
__global__ void logits_kernel(const float* __restrict__ x,
                              const float* __restrict__ gw,
                              const float* __restrict__ eb,
                              float* __restrict__ logits) {
  __shared__ float gws[ETOT * DMODEL];   // 48 KB
  int tid = threadIdx.x;
  const float4* gw4 = (const float4*)gw;
  float4* gws4 = (float4*)gws;
  #pragma unroll
  for (int i = 0; i < (ETOT * DMODEL / 4) / 256; i++)
    gws4[tid + i * 256] = gw4[tid + i * 256];
  __syncthreads();

  int sub = tid >> 4;
  int l16 = tid & 15;
  int tok = blockIdx.x * 16 + sub;
  const float4* xr = (const float4*)(x + (size_t)tok * DMODEL);

  float s[ETOT] = {};
  #pragma unroll
  for (int j = 0; j < 16; j++) {
    float4 xv = xr[l16 + j * 16];
    #pragma unroll
    for (int e = 0; e < ETOT; e++) {
      float4 g = gws4[e * (DMODEL / 4) + l16 + j * 16];
      s[e] += xv.x * g.x + xv.y * g.y + xv.z * g.z + xv.w * g.w;
    }
  }
  #pragma unroll
  for (int e = 0; e < ETOT; e++) {
    #pragma unroll
    for (int m = 8; m >= 1; m >>= 1) s[e] += __shfl_xor(s[e], m, 64);
  }
  if (l16 == 0) {
    #pragma unroll
    for (int e = 0; e < ETOT; e++)
      logits[(size_t)tok * ETOT + e] = s[e] + eb[e];
  }
}

// ---------------- routing phase B: top-2, softmax, counts ----------------
__global__ void topk_kernel(const float* __restrict__ logits,
                            int* __restrict__ cnt,
                            int* __restrict__ choice,
                            float* __restrict__ chw,
                            float* __restrict__ wz) {
  int t = blockIdx.x * blockDim.x + threadIdx.x;
  if (t >= NTOK) return;
  const float4* lr = (const float4*)(logits + (size_t)t * ETOT);
  float4 a = lr[0], b = lr[1], c = lr[2];
  float lg[ETOT] = { a.x, a.y, a.z, a.w, b.x, b.y, b.z, b.w, c.x, c.y, c.z, c.w };
  int i1 = 0; float m1 = lg[0];
  #pragma unroll
  for (int e = 1; e < ETOT; e++) if (lg[e] > m1) { m1 = lg[e]; i1 = e; }
  int i2 = -1; float m2 = -3.4e38f;
  #pragma unroll
  for (int e = 0; e < ETOT; e++) { if (e == i1) continue; if (lg[e] > m2) { m2 = lg[e]; i2 = e; } }
  float ex = expf(m2 - m1);
  float w0 = 1.f / (1.f + ex);
  float w1 = ex / (1.f + ex);
  int ee[2] = { i1, i2 };
  float ww[2] = { w0, w1 };
  float z = 0.f;
  #pragma unroll
  for (int k = 0; k < 2; k++) {
    choice[t * 2 + k] = ee[k];
    chw[t * 2 + k]    = ww[k];
    if (ee[k] < NEXP) atomicAdd(&cnt[ee[k]], 1);
    else              z += ww[k];
  }
  wz[t] = z;
}

// -------- scan + dense worklists: (expert|mb<<8) per working m-block ------
// (round-6 proven version; no holes, no padding)
__global__ void scan_kernel(const int* __restrict__ cnt,
                            int* __restrict__ offs,
                            int* __restrict__ cursor,
                            int* __restrict__ wl1, int* __restrict__ nw1,
                            int* __restrict__ wl2, int* __restrict__ nw2) {
  if (threadIdx.x == 0) {
    int a = 0;
    for (int e = 0; e < NEXP; e++) { offs[e] = a; cursor[e] = a; a += cnt[e]; }
    int n1 = 0, n2 = 0;
    for (int e = 0; e < NEXP; e++) {
      int c = cnt[e];
      for (int mb = 0; mb * 128 < c; mb++) wl1[n1++] = e | (mb << 8);
      for (int mb = 0; mb * 128 < c; mb++) wl2[n2++] = e | (mb << 8);
    }
    *nw1 = n1; *nw2 = n2;
  }
}

// ---------------- slot assignment (order nondeterministic, values not) ----
__global__ void assign_kernel(const int* __restrict__ choice,
                              int* __restrict__ cursor,
                              int* __restrict__ a_row,
                              int* __restrict__ tok_list) {
  int t = blockIdx.x * blockDim.x + threadIdx.x;
  if (t >= NTOK) return;
  #pragma unroll
  for (int k = 0; k < 2; k++) {
    int e = choice[2 * t + k];
    if (e < NEXP) {
      int pos = atomicAdd(&cursor[e], 1);
      a_row[2 * t + k] = pos;
      tok_list[pos] = t;
    } else {
      a_row[2 * t + k] = -1;
    }
  }
}

// ---------------- grouped GEMM, dbuf 2-phase, BMx128 tile, BK=32 ---------
// Dense worklist: block id = wb*NB + nb; wb indexes wl (packed e|mb<<8).
template <int BM, int NDIM, int KDIM, bool SILU, bool AGATHER>
__launch_bounds__(256)
__global__ void ffn_gemm(const unsigned short* __restrict__ Abf,
                         const unsigned short* __restrict__ Bw,
                         const int* __restrict__ cnt,
                         const int* __restrict__ offs,
                         const int* __restrict__ tok_list,
                         const int* __restrict__ wl,
                         const int* __restrict__ nwork,
                         unsigned short* __restrict__ OutBf,
                         float* __restrict__ OutF) {
  constexpr int NB = NDIM / 128;         // n-blocks (power of 2)
  constexpr int MI = BM / 32;            // m-frags per wave
  constexpr int AJ = BM / 64;            // A staging issues (64 rows each)
  int id = blockIdx.x;
  int nb = id & (NB - 1);
  int wb = id / NB;
  if (wb >= *nwork) return;
  int w  = wl[wb];
  int e  = w & 255;
  int mb = w >> 8;
  int count = cnt[e];
  int m0 = mb * BM;
  int off = offs[e];
  int n0 = nb * 128;
  const unsigned short* B = Bw + (size_t)e * NDIM * KDIM;

  __shared__ unsigned short lA[2][BM * 32];
  __shared__ unsigned short lB[2][128 * 32];

  int tid  = threadIdx.x;
  int lane = tid & 63;
  int wv = tid >> 6;
  int wm = wv >> 1, wn = wv & 1;
  int lr = lane & 15, lk8 = (lane >> 4) * 8;

  int srow = tid >> 2;
  int scol = (tid & 3) * 8;
  const unsigned short* aSrc[AJ];
  const unsigned short* bSrc[2];
  #pragma unroll
  for (int j = 0; j < AJ; j++) {
    int rr = m0 + j * 64 + srow;
    if (rr >= count) rr = count - 1;
    if (AGATHER) aSrc[j] = Abf + (size_t)tok_list[off + rr] * KDIM + scol;
    else         aSrc[j] = Abf + (size_t)(off + rr) * KDIM + scol;
  }
  #pragma unroll
  for (int j = 0; j < 2; j++)
    bSrc[j] = B + (size_t)(n0 + j * 64 + srow) * KDIM + scol;

  f32x4 acc[MI][4] = {};

#define STAGE(b, kk)                                                        \
  do {                                                                      \
    int kb_ = (kk) * 32;                                                    \
    _Pragma("unroll")                                                       \
    for (int j = 0; j < AJ; j++) G2L16(aSrc[j] + kb_, &lA[b][j * 2048 + tid * 8]); \
    _Pragma("unroll")                                                       \
    for (int j = 0; j < 2; j++)  G2L16(bSrc[j] + kb_, &lB[b][j * 2048 + tid * 8]); \
  } while (0)

#define COMPUTE(b)                                                          \
  do {                                                                      \
    bf16x8 af[MI], bq[4];                                                   \
    _Pragma("unroll")                                                       \
    for (int mi = 0; mi < MI; mi++)                                         \
      af[mi] = *(const bf16x8*)&lA[b][(wm * (BM / 2) + mi * 16 + lr) * 32 + lk8]; \
    _Pragma("unroll")                                                       \
    for (int ni = 0; ni < 4; ni++)                                          \
      bq[ni] = *(const bf16x8*)&lB[b][(wn * 64 + ni * 16 + lr) * 32 + lk8]; \
    _Pragma("unroll")                                                       \
    for (int mi = 0; mi < MI; mi++)                                         \
      _Pragma("unroll")                                                     \
      for (int ni = 0; ni < 4; ni++)                                        \
        acc[mi][ni] = __builtin_amdgcn_mfma_f32_16x16x32_bf16(af[mi], bq[ni], acc[mi][ni], 0, 0, 0); \
  } while (0)

  constexpr int NK = KDIM / 32;   // even
  STAGE(0, 0);
  __syncthreads();
  #pragma unroll 1
  for (int kk = 0; kk < NK; kk += 2) {
    if (kk + 1 < NK) STAGE(1, kk + 1);
    COMPUTE(0);
    __syncthreads();
    if (kk + 1 < NK) {
      if (kk + 2 < NK) STAGE(0, kk + 2);
      COMPUTE(1);
      __syncthreads();
    }
  }
#undef STAGE
#undef COMPUTE

  // epilogue: C/D layout col=lane&15, row=(lane>>4)*4+i  [m89-verified]
  int rb = (lane >> 4) * 4;
  #pragma unroll
  for (int mi = 0; mi < MI; mi++) {
    #pragma unroll
    for (int i = 0; i < 4; i++) {
      int grow = m0 + wm * (BM / 2) + mi * 16 + rb + i;
      if (grow >= count) continue;
      #pragma unroll
      for (int ni = 0; ni < 4; ni++) {
        int gcol = n0 + wn * 64 + ni * 16 + lr;
        float v = acc[mi][ni][i];
        if (SILU) {
          // silu(v) = v * rcp(1 + exp2(-v*log2e)) — fast HW transcendentals
          float s = v * __builtin_amdgcn_rcpf(
                        1.f + __builtin_amdgcn_exp2f(-v * 1.44269504088896f));
          OutBf[(size_t)(off + grow) * NDIM + gcol] = f2bf(s);
        } else {
          OutF[(size_t)(off + grow) * NDIM + gcol] = v;
        }
      }
    }
  }
}

// ---------------- final combine: out = wz*x + sum_k w_k * Y[row_k] --------
__global__ void combine_kernel(const float* __restrict__ x,
                               const float* __restrict__ Y,
                               const int* __restrict__ a_row,
                               const float* __restrict__ chw,
                               const float* __restrict__ wz,
                               float* __restrict__ out) {
  int t = blockIdx.x;
  int d = threadIdx.x * 4;
  const float4 xv = *(const float4*)&x[(size_t)t * DMODEL + d];
  float z = wz[t];
  float4 o; o.x = z * xv.x; o.y = z * xv.y; o.z = z * xv.z; o.w = z * xv.w;
  #pragma unroll
  for (int k = 0; k < 2; k++) {
    int r = a_row[2 * t + k];
    if (r >= 0) {
      float w = chw[2 * t + k];
      const float4 yv = *(const float4*)&Y[(size_t)r * DMODEL + d];
      o.x += w * yv.x; o.y += w * yv.y; o.z += w * yv.z; o.w += w * yv.w;
    }
  }
  *(float4*)&out[(size_t)t * DMODEL + d] = o;
}

extern "C" void kernel_launch(void* const* d_in, const int* in_sizes, int n_in,
                              void* d_out, int out_size, void* d_ws, size_t ws_size,
                              hipStream_t stream) {
  const float* x  = (const float*)d_in[0];   // (2,2048,1024)
  const float* gw = (const float*)d_in[1];   // (12,1024)
  const float* eb = (const float*)d_in[2];   // (12,)
  const float* w1 = (const float*)d_in[3];   // (8,2048,1024)
  const float* w2 = (const float*)d_in[4];   // (8,1024,2048)
  float* out = (float*)d_out;

  char* ws = (char*)d_ws;
  size_t o = 0;
  int*   cnt     = (int*)(ws + o);  o += 8 * sizeof(int);
  int*   offs    = (int*)(ws + o);  o += 8 * sizeof(int);
  int*   cursor  = (int*)(ws + o);  o += 8 * sizeof(int);
  int*   nw1     = (int*)(ws + o);  o += sizeof(int);
  int*   nw2     = (int*)(ws + o);  o += sizeof(int);
  o = (o + 255) & ~(size_t)255;
  int*   wl1     = (int*)(ws + o);  o += WL1MAX * sizeof(int);
  int*   wl2     = (int*)(ws + o);  o += WL2MAX * sizeof(int);
  o = (o + 255) & ~(size_t)255;
  int*   choice  = (int*)(ws + o);  o += (size_t)2 * NTOK * sizeof(int);
  float* chw     = (float*)(ws + o); o += (size_t)2 * NTOK * sizeof(float);
  float* wzv     = (float*)(ws + o); o += (size_t)NTOK * sizeof(float);
  int*   a_row   = (int*)(ws + o);  o += (size_t)2 * NTOK * sizeof(int);
  int*   tok     = (int*)(ws + o);  o += (size_t)MAXA * sizeof(int);
  float* logits  = (float*)(ws + o); o += (size_t)NTOK * ETOT * sizeof(float);
  o = (o + 255) & ~(size_t)255;
  unsigned short* Xb  = (unsigned short*)(ws + o); o += (size_t)NTOK * DMODEL * sizeof(unsigned short);
  unsigned short* W1b = (unsigned short*)(ws + o); o += (size_t)NEXP * DFFN * DMODEL * sizeof(unsigned short);
  unsigned short* W2b = (unsigned short*)(ws + o); o += (size_t)NEXP * DMODEL * DFFN * sizeof(unsigned short);
  unsigned short* H   = (unsigned short*)(ws + o); o += (size_t)MAXA * DFFN * sizeof(unsigned short);
  // Y aliases W1b (33.55 MB each): W1b is dead after GEMM1, GEMM2 reads only H+W2b.
  float* Y = (float*)W1b;

  hipMemsetAsync(cnt, 0, 8 * sizeof(int), stream);

  cvt3_kernel<<<dim3(4096), dim3(256), 0, stream>>>(
      w1, W1b, (NEXP * DFFN * DMODEL) / 8,
      w2, W2b, (NEXP * DMODEL * DFFN) / 8,
      x,  Xb,  (NTOK * DMODEL) / 8);

  logits_kernel<<<dim3(NTOK / 16), dim3(256), 0, stream>>>(x, gw, eb, logits);
  topk_kernel<<<dim3(NTOK / 256), dim3(256), 0, stream>>>(logits, cnt, choice, chw, wzv);
  scan_kernel<<<dim3(1), dim3(64), 0, stream>>>(cnt, offs, cursor, wl1, nw1, wl2, nw2);
  assign_kernel<<<dim3(NTOK / 256), dim3(256), 0, stream>>>(choice, cursor, a_row, tok);

  // GEMM1: H = silu(Xb @ W1b^T)   M<=cnt[e], N=2048, K=1024; BM=128
  ffn_gemm<128, DFFN, DMODEL, true, true>
      <<<dim3(WL1MAX * (DFFN / 128)), dim3(256), 0, stream>>>(
      Xb, W1b, cnt, offs, tok, wl1, nw1, H, nullptr);
  // GEMM2: Y = H @ W2b^T          M<=cnt[e], N=1024, K=2048; BM=128
  ffn_gemm<128, DMODEL, DFFN, false, false>
      <<<dim3(WL2MAX * (DMODEL / 128)), dim3(256), 0, stream>>>(
      H, W2b, cnt, offs, tok, wl2, nw2, nullptr, Y);

  combine_kernel<<<dim3(NTOK), dim3(256), 0, stream>>>(x, Y, a_row, chw, wzv, out);
}